// Round 3
// baseline (731.271 us; speedup 1.0000x reference)
//
#include <hip/hip_runtime.h>
#include <cstdint>
#include <cstddef>

#define BB 4
#define CC 19
#define HH 512
#define WW 1024
#define HW (HH*WW)          // 524288
#define HW4 (HW/4)          // 131072
#define KTOP 256
#define EPSF 1e-6f
#define NB1 4096            // coarse bins: key >> 20
#define NB2 8192            // refine bins: (key >> 7) & 0x1FFF
#define LSTRIDE 1032        // padded LDS row stride, data at col 4..1027
#define LOGC 2.9444389791664403f   // ln(19)

#define NSEG 64             // segments per image (8 rows each)
#define RPB 8               // rows per block
#define NBLK (BB*NSEG)      // 256 blocks == 1 per CU (co-resident by capacity)
#define TPB 1024            // 16 waves/CU

__device__ __forceinline__ unsigned int sortable(float x) {
    unsigned int u = __float_as_uint(x);
    return (u & 0x80000000u) ? ~u : (u | 0x80000000u);
}
__device__ __forceinline__ float unsortable(unsigned int K) {
    unsigned int u = (K & 0x80000000u) ? (K & 0x7FFFFFFFu) : ~K;
    return __uint_as_float(u);
}

// ---- grid barrier: sense-reversing, device(agent)-scope (Guideline 16) ----
__device__ __forceinline__ void gbar(unsigned int* cnt, unsigned int* gen) {
    __threadfence();                         // release this thread's prior writes
    __syncthreads();                         // whole block arrived + fenced
    if (threadIdx.x == 0) {
        unsigned int g = __hip_atomic_load(gen, __ATOMIC_RELAXED, __HIP_MEMORY_SCOPE_AGENT);
        unsigned int a = __hip_atomic_fetch_add(cnt, 1u, __ATOMIC_ACQ_REL, __HIP_MEMORY_SCOPE_AGENT);
        if (a == NBLK - 1u) {
            __hip_atomic_store(cnt, 0u, __ATOMIC_RELAXED, __HIP_MEMORY_SCOPE_AGENT);
            __hip_atomic_fetch_add(gen, 1u, __ATOMIC_RELEASE, __HIP_MEMORY_SCOPE_AGENT);
        } else {
            while (__hip_atomic_load(gen, __ATOMIC_ACQUIRE, __HIP_MEMORY_SCOPE_AGENT) == g)
                __builtin_amdgcn_s_sleep(16);
        }
    }
    __syncthreads();
    __threadfence();                         // acquire side: drop stale cached lines
}

// ---- LDS phase union ----
struct P1Mem {
    float ent_s[(RPB + 2) * LSTRIDE];          // 41280 B
    unsigned char pred_s[(RPB + 2) * LSTRIDE]; // 10320 B
    unsigned int lh1[NB1];                     // 16384 B
};
struct P2Mem {
    unsigned int lh2[NB2];                     // 32768 B
    float ls2[NB2];                            // 32768 B
};
union UMem { P1Mem p1; P2Mem p2; };            // 67984 B

// ---- top-down bin selection over NBINS = 1024*CPT, 1024 threads ----
// finds largest bin with suffix_count >= rem; rem_out = rem - suffix_count(bin+1)
template<int CPT>
__device__ __forceinline__ void sel_topdown(const unsigned int* __restrict__ hb,
                                            int rem, unsigned int* cs, unsigned int* bs,
                                            int* s3, int* bin_out, int* rem_out) {
    int t = threadIdx.x;
    unsigned int s = 0;
#pragma unroll
    for (int i = 0; i < CPT; ++i) s += hb[t * CPT + i];
    cs[t] = s;
    __syncthreads();
    for (int d = 1; d < 1024; d <<= 1) {       // suffix scan over 1024 chunks
        unsigned int v = (t + d < 1024) ? cs[t + d] : 0;
        __syncthreads();
        cs[t] += v;
        __syncthreads();
    }
    unsigned int St = cs[t];
    unsigned int St1 = (t < 1023) ? cs[t + 1] : 0;
    if ((int)St >= rem && (t == 1023 || (int)St1 < rem)) {
        s3[0] = t; s3[2] = rem - (int)St1;
    }
    __syncthreads();
    int chunk = s3[0], rem2 = s3[2];
    if (t < CPT) bs[t] = hb[chunk * CPT + t];
    __syncthreads();
    if (t == 0) {                              // tiny within-chunk suffix walk
        int acc = 0, bin = chunk * CPT, rr = rem2;
        for (int j = CPT - 1; j >= 0; --j) {
            acc += (int)bs[j];
            if (acc >= rem2) { bin = chunk * CPT + j; rr = rem2 - (acc - (int)bs[j]); break; }
        }
        s3[1] = bin; s3[2] = rr;
    }
    __syncthreads();
    *bin_out = s3[1];
    *rem_out = s3[2];
}

// ---- init: zero hist1|hist2|hsum|barrier + out (replaces in-kernel init) ----
__global__ __launch_bounds__(1024) void k_init(unsigned int* __restrict__ histb,
                                               float* __restrict__ out) {
    int i = blockIdx.x * 1024 + threadIdx.x;
    if (i < 81922) histb[i] = 0u;              // 81920 hist words + bar cnt + bar gen
    if (i < BB) out[i] = 0.f;
}

// ==================== fused persistent kernel ====================
__global__ __launch_bounds__(1024) void k_fused(const float* __restrict__ logit,
                                                float* __restrict__ ent,
                                                unsigned char* __restrict__ pred,
                                                unsigned int* __restrict__ histb,
                                                float* __restrict__ out) {
    __shared__ __align__(16) UMem U;
    __shared__ float lgt[48];
    __shared__ unsigned int cs[1024];
    __shared__ unsigned int bs[8];
    __shared__ int s3[3];
    __shared__ float red[16];

    int tid = threadIdx.x;
    int tx = tid & 255;                 // quad column
    int ty = tid >> 8;                  // 0..3
    int b = blockIdx.x >> 6;            // image
    int seg = blockIdx.x & (NSEG - 1);  // 8-row segment
    int r0 = seg * RPB;

    unsigned int* hist1 = histb;                      // 4*4096 words
    unsigned int* hist2 = histb + 16384;              // 4*8192 words
    float*        hsum  = (float*)(histb + 49152);    // 4*8192 words
    unsigned int* bcnt  = histb + 81920;
    unsigned int* bgen  = histb + 81921;

    if (tid < 48) {
        int nvi = tid >> 4, cnt = tid & 15;
        float nv = (nvi == 0) ? 4.f : (nvi == 1) ? 6.f : 9.f;
        lgt[tid] = __logf((float)cnt / nv + EPSF);
    }
    for (int i = tid; i < (RPB + 2) * LSTRIDE; i += TPB) { U.p1.ent_s[i] = 0.f; U.p1.pred_s[i] = 255; }
    for (int i = tid; i < NB1; i += TPB) U.p1.lh1[i] = 0;
    __syncthreads();

    // ---------------- P0: entropy + argmax for own 8 rows ----------------
    {
        const float4* bb4 = (const float4*)logit + (size_t)b * CC * HW4;
#pragma unroll
        for (int it = 0; it < 2; ++it) {
            int lr = ty + it * 4;                 // local row 0..7
            int q = (r0 + lr) * 256 + tx;         // quad index in image
            const float4* basep = bb4 + q;
            float e0 = 0.f, e1 = 0.f, e2 = 0.f, e3 = 0.f;
            float m0 = -1.f, m1 = -1.f, m2 = -1.f, m3 = -1.f;
            int a0 = 0, a1 = 0, a2 = 0, a3 = 0;
#pragma unroll
            for (int c = 0; c < CC; ++c) {
                float4 p = basep[(size_t)c * HW4];
                e0 -= p.x * __logf(p.x + EPSF); if (p.x > m0) { m0 = p.x; a0 = c; }
                e1 -= p.y * __logf(p.y + EPSF); if (p.y > m1) { m1 = p.y; a1 = c; }
                e2 -= p.z * __logf(p.z + EPSF); if (p.z > m2) { m2 = p.z; a2 = c; }
                e3 -= p.w * __logf(p.w + EPSF); if (p.w > m3) { m3 = p.w; a3 = c; }
            }
            float4 ev = make_float4(e0, e1, e2, e3);
            unsigned int pw = (unsigned int)a0 | ((unsigned int)a1 << 8) |
                              ((unsigned int)a2 << 16) | ((unsigned int)a3 << 24);
            *(float4*)&U.p1.ent_s[(lr + 1) * LSTRIDE + 4 + tx * 4] = ev;
            *(unsigned int*)&U.p1.pred_s[(lr + 1) * LSTRIDE + 4 + tx * 4] = pw;
            if (lr == 0 || lr == RPB - 1) {       // boundary rows: neighbors' halo
                *((float4*)ent + (size_t)b * HW4 + q) = ev;
                ((unsigned int*)pred)[(size_t)b * HW4 + q] = pw;
            }
        }
    }
    gbar(bcnt, bgen);

    // ---------------- P1: stage 2 halo rows + score 8 px/thread ----------------
    if (tid < 512) {                              // 2 rows x 256 quads
        int top = tid >> 8;                       // 0 or 1
        int c4 = tid & 255;
        int rr = top * (RPB + 1);                 // LDS row 0 or 9
        int g = r0 - 1 + top * (RPB + 1);         // global row r0-1 or r0+8
        if (g >= 0 && g < HH) {
            float4 v = *((const float4*)ent + (size_t)b * HW4 + (size_t)g * 256 + c4);
            *(float4*)&U.p1.ent_s[rr * LSTRIDE + 4 + c4 * 4] = v;
            unsigned int pw = ((const unsigned int*)pred)[(size_t)b * HW4 + (size_t)g * 256 + c4];
            *(unsigned int*)&U.p1.pred_s[rr * LSTRIDE + 4 + c4 * 4] = pw;
        }
    }
    __syncthreads();

    float sv[8];                                  // thread owns rows r0+ty, r0+ty+4; cols 4tx..4tx+3
#pragma unroll
    for (int it = 0; it < 2; ++it) {
        int k = ty + it * 4;                      // local pixel row
        float r3[3][6];
        int p3[3][6];
#pragma unroll
        for (int rr = 0; rr < 3; ++rr) {          // window rows k..k+2 (global h-1..h+1)
            const float* rowp = &U.p1.ent_s[(k + rr) * LSTRIDE + 4];
            const unsigned char* prow = &U.p1.pred_s[(k + rr) * LSTRIDE + 4];
            float4 m = *(const float4*)&rowp[tx * 4];
            r3[rr][0] = rowp[tx * 4 - 1];         // col pad (0) at w==0 edge
            r3[rr][1] = m.x; r3[rr][2] = m.y; r3[rr][3] = m.z; r3[rr][4] = m.w;
            r3[rr][5] = rowp[tx * 4 + 4];
            uchar4 pm = *(const uchar4*)&prow[tx * 4];
            p3[rr][0] = prow[tx * 4 - 1];         // 255 pad
            p3[rr][1] = pm.x; p3[rr][2] = pm.y; p3[rr][3] = pm.z; p3[rr][4] = pm.w;
            p3[rr][5] = prow[tx * 4 + 4];
        }
        int h = r0 + k;
        int hn = (h > 0) + (h < HH - 1) + 1;
#pragma unroll
        for (int q = 0; q < 4; ++q) {
            int w = tx * 4 + q;
            float es = 0.f;
#pragma unroll
            for (int i = 0; i < 9; ++i) es += r3[i / 3][q + i % 3];   // same add order
            int cls[9];
#pragma unroll
            for (int i = 0; i < 9; ++i) cls[i] = p3[i / 3][q + i % 3];
            int nv = hn * ((w > 0) + (w < WW - 1) + 1);
            float inv = 1.f / (float)nv;
            int nvi = (nv == 9) ? 2 : ((nv == 6) ? 1 : 0);
            const float* lg = &lgt[nvi * 16];
            float lsum = 0.f;
#pragma unroll
            for (int i = 0; i < 9; ++i) {
                int cnt = 0;
#pragma unroll
                for (int j = 0; j < 9; ++j) cnt += (cls[j] == cls[i]) ? 1 : 0;
                float lv = lg[cnt];
                lsum += (cls[i] != 255) ? lv : 0.f;
            }
            float imp = -inv * lsum;
            float v = (es * (1.f / (9.f * LOGC))) * (imp * (1.f / LOGC));
            sv[it * 4 + q] = v;
            atomicAdd(&U.p1.lh1[sortable(v) >> 20], 1u);
        }
    }
    __syncthreads();
    {
        unsigned int* hb = hist1 + (size_t)b * NB1;
        for (int i = tid; i < NB1; i += TPB) {
            unsigned int c = U.p1.lh1[i];
            if (c) atomicAdd(&hb[i], c);
        }
    }
    gbar(bcnt, bgen);

    // ---------------- P2: coarse select + refine hist + strict-above sum ----------------
    int bin1, rem1;
    sel_topdown<4>(hist1 + (size_t)b * NB1, KTOP, cs, bs, s3, &bin1, &rem1);
    unsigned int t1 = (unsigned int)bin1;
    for (int i = tid; i < NB2; i += TPB) { U.p2.lh2[i] = 0; U.p2.ls2[i] = 0.f; }
    __syncthreads();
    float sa = 0.f;                               // sum strictly above the T1 coarse bin
#pragma unroll
    for (int j = 0; j < 8; ++j) {
        float vv = sv[j];
        unsigned int k = sortable(vv);
        unsigned int cb = k >> 20;
        if (cb > t1) sa += vv;
        else if (cb == t1) {
            int sub = (k >> 7) & 0x1FFF;
            atomicAdd(&U.p2.lh2[sub], 1u);
            atomicAdd(&U.p2.ls2[sub], vv);
        }
    }
    __syncthreads();
    {
        unsigned int* hb = hist2 + (size_t)b * NB2;
        float* sb = hsum + (size_t)b * NB2;
        for (int i = tid; i < NB2; i += TPB) {
            unsigned int c = U.p2.lh2[i];
            if (c) { atomicAdd(&hb[i], c); atomicAdd(&sb[i], U.p2.ls2[i]); }
        }
    }
#pragma unroll
    for (int d = 32; d; d >>= 1) sa += __shfl_down(sa, d);
    if ((tid & 63) == 0) red[tid >> 6] = sa;
    __syncthreads();
    if (tid == 0) {
        float tt = 0.f;
#pragma unroll
        for (int i = 0; i < 16; ++i) tt += red[i];
        if (tt != 0.f) atomicAdd(&out[b], tt);
    }
    gbar(bcnt, bgen);

    // ---------------- P3: final threshold + tail sums (seg==0 blocks) ----------------
    if (seg == 0) {
        int bin, rem;
        sel_topdown<8>(hist2 + (size_t)b * NB2, rem1, cs, bs, s3, &bin, &rem);
        const float* sb = hsum + (size_t)b * NB2;
        float* rsf = (float*)cs;                  // reuse scan scratch
        float s = 0.f;
        for (int i = tid; i < NB2; i += TPB) if (i > bin) s += sb[i];
        rsf[tid] = s;
        __syncthreads();
        for (int d = 512; d; d >>= 1) {
            if (tid < d) rsf[tid] += rsf[tid + d];
            __syncthreads();
        }
        if (tid == 0) {
            unsigned int K = (t1 << 20) | ((unsigned int)bin << 7);
            atomicAdd(&out[b], rsf[0] + unsortable(K) * (float)rem);  // ties at bin edge
        }
    }
}

extern "C" void kernel_launch(void* const* d_in, const int* in_sizes, int n_in,
                              void* d_out, int out_size, void* d_ws, size_t ws_size,
                              hipStream_t stream) {
    const float* logit = (const float*)d_in[0];
    float* out = (float*)d_out;
    char* ws = (char*)d_ws;

    // workspace layout
    float*         ent   = (float*)(ws);                       // 8,388,608 B (boundary rows only)
    unsigned char* pred  = (unsigned char*)(ws + 8388608);     // 2,097,152 B
    unsigned int*  histb = (unsigned int*)(ws + 10485760);     // hist1|hist2|hsum|bar = 81922 words

    k_init<<<81, 1024, 0, stream>>>(histb, out);
    k_fused<<<NBLK, TPB, 0, stream>>>(logit, ent, pred, histb, out);
}

// Round 4
// 289.908 us; speedup vs baseline: 2.5224x; 2.5224x over previous
//
#include <hip/hip_runtime.h>
#include <cstdint>
#include <cstddef>

#define BB 4
#define CC 19
#define HH 512
#define WW 1024
#define HW (HH*WW)          // 524288
#define HW4 (HW/4)          // 131072
#define KTOP 256
#define EPSF 1e-6f
#define NB1 4096            // coarse bins: key >> 20
#define NB2 8192            // refine bins: (key >> 7) & 0x1FFF
#define LSTRIDE 1032        // padded LDS row stride, data at col 4..1027
#define LOGC 2.9444389791664403f   // ln(19)

#define NSEG 64             // segments per image (8 rows each) for kernel A
#define RPB 8               // rows per block (A)
#define NBLK (BB*NSEG)      // 256 blocks, 1/CU (LDS-forced), co-resident (proven R3)
#define SEGF 128            // segments per image for kernel B (4 rows each)

__device__ __forceinline__ unsigned int sortable(float x) {
    unsigned int u = __float_as_uint(x);
    return (u & 0x80000000u) ? ~u : (u | 0x80000000u);
}
__device__ __forceinline__ float unsortable(unsigned int K) {
    unsigned int u = (K & 0x80000000u) ? (K & 0x7FFFFFFFu) : ~K;
    return __uint_as_float(u);
}
// relaxed agent-scope atomics: cross-XCD coherent, NO L2 flush (Guideline 16)
__device__ __forceinline__ unsigned int agld(const unsigned int* p) {
    return __hip_atomic_load(p, __ATOMIC_RELAXED, __HIP_MEMORY_SCOPE_AGENT);
}
__device__ __forceinline__ void agst(unsigned int* p, unsigned int v) {
    __hip_atomic_store(p, v, __ATOMIC_RELAXED, __HIP_MEMORY_SCOPE_AGENT);
}

// ---- kernel A LDS: pad > 80 KB to force 1 block/CU (even spread, fat VGPR) ----
struct P1Mem {
    float ent_s[(RPB + 2) * LSTRIDE];          // 41280 B
    unsigned char pred_s[(RPB + 2) * LSTRIDE]; // 10320 B
    unsigned int lh1[NB1];                     // 16384 B
};
union UMem { P1Mem p1; unsigned char pad[82000]; };

// ---- init: zero hist1|hist2|hsum|flags|done + out ----
__global__ __launch_bounds__(1024) void k_init(unsigned int* __restrict__ histb,
                                               float* __restrict__ out) {
    int i = blockIdx.x * 1024 + threadIdx.x;
    if (i < 82180) histb[i] = 0u;     // 81920 hist + 256 flags + 4 done
    if (i < BB) out[i] = 0.f;
}

// ==================== kernel A: entropy + halo handshake + score + hist1 ====================
__global__ __launch_bounds__(1024, 4) void k_A(const float* __restrict__ logit,
                                               float* __restrict__ ent,
                                               unsigned char* __restrict__ pred,
                                               float* __restrict__ score,
                                               unsigned int* __restrict__ histb) {
    __shared__ __align__(16) UMem U;
    __shared__ float lgt[48];
    int tid = threadIdx.x;
    int tx = tid & 255;                 // quad column
    int ty = tid >> 8;                  // 0..3
    int b = blockIdx.x >> 6;            // image
    int seg = blockIdx.x & (NSEG - 1);  // 8-row segment
    int r0 = seg * RPB;

    unsigned int* hist1 = histb;                      // 4*4096 words
    unsigned int* flags = histb + 81920;              // 256 words

    if (tid < 48) {
        int nvi = tid >> 4, cnt = tid & 15;
        float nv = (nvi == 0) ? 4.f : (nvi == 1) ? 6.f : 9.f;
        lgt[tid] = __logf((float)cnt / nv + EPSF);
    }
    for (int i = tid; i < (RPB + 2) * LSTRIDE; i += 1024) { U.p1.ent_s[i] = 0.f; U.p1.pred_s[i] = 255; }
    for (int i = tid; i < NB1; i += 1024) U.p1.lh1[i] = 0;
    __syncthreads();

    // ---------------- P0: entropy + argmax for own 8 rows ----------------
    {
        const float4* bb4 = (const float4*)logit + (size_t)b * CC * HW4;
#pragma unroll
        for (int it = 0; it < 2; ++it) {
            int lr = ty + it * 4;                 // local row 0..7
            int q = (r0 + lr) * 256 + tx;         // quad index in image
            const float4* basep = bb4 + q;
            float e0 = 0.f, e1 = 0.f, e2 = 0.f, e3 = 0.f;
            float m0 = -1.f, m1 = -1.f, m2 = -1.f, m3 = -1.f;
            int a0 = 0, a1 = 0, a2 = 0, a3 = 0;
#pragma unroll
            for (int c = 0; c < CC; ++c) {
                float4 p = basep[(size_t)c * HW4];
                e0 -= p.x * __logf(p.x + EPSF); if (p.x > m0) { m0 = p.x; a0 = c; }
                e1 -= p.y * __logf(p.y + EPSF); if (p.y > m1) { m1 = p.y; a1 = c; }
                e2 -= p.z * __logf(p.z + EPSF); if (p.z > m2) { m2 = p.z; a2 = c; }
                e3 -= p.w * __logf(p.w + EPSF); if (p.w > m3) { m3 = p.w; a3 = c; }
            }
            *(float4*)&U.p1.ent_s[(lr + 1) * LSTRIDE + 4 + tx * 4] = make_float4(e0, e1, e2, e3);
            unsigned int pw = (unsigned int)a0 | ((unsigned int)a1 << 8) |
                              ((unsigned int)a2 << 16) | ((unsigned int)a3 << 24);
            *(unsigned int*)&U.p1.pred_s[(lr + 1) * LSTRIDE + 4 + tx * 4] = pw;
            if (lr == 0 || lr == RPB - 1) {       // boundary rows -> relaxed agent atomics
                unsigned int* ep = (unsigned int*)ent + (size_t)b * HW + (size_t)(r0 + lr) * WW + tx * 4;
                agst(ep + 0, __float_as_uint(e0));
                agst(ep + 1, __float_as_uint(e1));
                agst(ep + 2, __float_as_uint(e2));
                agst(ep + 3, __float_as_uint(e3));
                agst((unsigned int*)pred + (size_t)b * HW4 + (size_t)(r0 + lr) * 256 + tx, pw);
            }
        }
    }
    __syncthreads();        // implicit vmcnt(0)/wave: all boundary agst completed
    if (tid == 0) agst(&flags[blockIdx.x], 1u);          // publish
    if (tid == 64 && seg > 0)                            // spin on neighbors (separate waves)
        while (agld(&flags[blockIdx.x - 1]) == 0u) __builtin_amdgcn_s_sleep(2);
    if (tid == 128 && seg < NSEG - 1)
        while (agld(&flags[blockIdx.x + 1]) == 0u) __builtin_amdgcn_s_sleep(2);
    __syncthreads();

    // ---------------- stage 2 halo rows (relaxed atomic loads) ----------------
    if (tid < 512) {                              // 2 rows x 256 quads
        int top = tid >> 8;                       // 0 or 1
        int c4 = tid & 255;
        int rr = top * (RPB + 1);                 // LDS row 0 or 9
        int g = r0 - 1 + top * (RPB + 1);         // global row r0-1 or r0+8
        if (g >= 0 && g < HH) {
            const unsigned int* eu = (const unsigned int*)ent + (size_t)b * HW + (size_t)g * WW + c4 * 4;
            float4 v;
            v.x = __uint_as_float(agld(eu + 0));
            v.y = __uint_as_float(agld(eu + 1));
            v.z = __uint_as_float(agld(eu + 2));
            v.w = __uint_as_float(agld(eu + 3));
            *(float4*)&U.p1.ent_s[rr * LSTRIDE + 4 + c4 * 4] = v;
            unsigned int pw = agld((const unsigned int*)pred + (size_t)b * HW4 + (size_t)g * 256 + c4);
            *(unsigned int*)&U.p1.pred_s[rr * LSTRIDE + 4 + c4 * 4] = pw;
        }
    }
    __syncthreads();

    // ---------------- score 8 px/thread -> score buffer + hist1 ----------------
    float* sbuf = score + (size_t)b * HW;
#pragma unroll
    for (int it = 0; it < 2; ++it) {
        int k = ty + it * 4;                      // local pixel row
        float r3[3][6];
        int p3[3][6];
#pragma unroll
        for (int rr = 0; rr < 3; ++rr) {          // window rows (global h-1..h+1)
            const float* rowp = &U.p1.ent_s[(k + rr) * LSTRIDE + 4];
            const unsigned char* prow = &U.p1.pred_s[(k + rr) * LSTRIDE + 4];
            float4 m = *(const float4*)&rowp[tx * 4];
            r3[rr][0] = rowp[tx * 4 - 1];         // col pad (0) at w==0 edge
            r3[rr][1] = m.x; r3[rr][2] = m.y; r3[rr][3] = m.z; r3[rr][4] = m.w;
            r3[rr][5] = rowp[tx * 4 + 4];
            uchar4 pm = *(const uchar4*)&prow[tx * 4];
            p3[rr][0] = prow[tx * 4 - 1];         // 255 pad
            p3[rr][1] = pm.x; p3[rr][2] = pm.y; p3[rr][3] = pm.z; p3[rr][4] = pm.w;
            p3[rr][5] = prow[tx * 4 + 4];
        }
        int h = r0 + k;
        int hn = (h > 0) + (h < HH - 1) + 1;
        float sv[4];
#pragma unroll
        for (int q = 0; q < 4; ++q) {
            int w = tx * 4 + q;
            float es = 0.f;
#pragma unroll
            for (int i = 0; i < 9; ++i) es += r3[i / 3][q + i % 3];   // same add order
            int cls[9];
#pragma unroll
            for (int i = 0; i < 9; ++i) cls[i] = p3[i / 3][q + i % 3];
            int nv = hn * ((w > 0) + (w < WW - 1) + 1);
            float inv = 1.f / (float)nv;
            int nvi = (nv == 9) ? 2 : ((nv == 6) ? 1 : 0);
            const float* lg = &lgt[nvi * 16];
            float lsum = 0.f;
#pragma unroll
            for (int i = 0; i < 9; ++i) {
                int cnt = 0;
#pragma unroll
                for (int j = 0; j < 9; ++j) cnt += (cls[j] == cls[i]) ? 1 : 0;
                float lv = lg[cnt];
                lsum += (cls[i] != 255) ? lv : 0.f;
            }
            float imp = -inv * lsum;
            float v = (es * (1.f / (9.f * LOGC))) * (imp * (1.f / LOGC));
            sv[q] = v;
            atomicAdd(&U.p1.lh1[sortable(v) >> 20], 1u);
        }
        *(float4*)&sbuf[(size_t)h * WW + tx * 4] = make_float4(sv[0], sv[1], sv[2], sv[3]);
    }
    __syncthreads();
    {
        unsigned int* hb = hist1 + (size_t)b * NB1;
        for (int i = tid; i < NB1; i += 1024) {
            unsigned int c = U.p1.lh1[i];
            if (c) atomicAdd(&hb[i], c);
        }
    }
}

// ------- 256-thread coarse selection (hist1 launch-coherent: plain loads) -------
__device__ __forceinline__ void select4k(const unsigned int* __restrict__ hb,
                                         int rem, int* bin_out, int* rem_out) {
    __shared__ unsigned int cs[256];
    __shared__ unsigned int bs[16];
    __shared__ int s_chunk, s_bin, s_rem;
    int t = threadIdx.x;
    unsigned int s = 0;
#pragma unroll
    for (int i = 0; i < 16; ++i) s += hb[t * 16 + i];
    cs[t] = s;
    __syncthreads();
    for (int d = 1; d < 256; d <<= 1) {           // suffix scan
        unsigned int v = (t + d < 256) ? cs[t + d] : 0;
        __syncthreads();
        cs[t] += v;
        __syncthreads();
    }
    unsigned int St = cs[t];
    unsigned int St1 = (t < 255) ? cs[t + 1] : 0;
    if ((int)St >= rem && (t == 255 || (int)St1 < rem)) {
        s_chunk = t; s_rem = rem - (int)St1;
    }
    __syncthreads();
    int chunk = s_chunk, rem2 = s_rem;
    if (t < 16) bs[t] = hb[chunk * 16 + t];
    __syncthreads();
    for (int d = 1; d < 16; d <<= 1) {
        unsigned int v = (t < 16 && t + d < 16) ? bs[t + d] : 0;
        __syncthreads();
        if (t < 16) bs[t] += v;
        __syncthreads();
    }
    if (t < 16) {
        unsigned int Sb = bs[t];
        unsigned int Sb1 = (t < 15) ? bs[t + 1] : 0;
        if ((int)Sb >= rem2 && (t == 15 || (int)Sb1 < rem2)) {
            s_bin = chunk * 16 + t; s_rem = rem2 - (int)Sb1;
        }
    }
    __syncthreads();
    *bin_out = s_bin;
    *rem_out = s_rem;
}

// ------- 256-thread fine selection over hist2 (same-kernel writes: agld) -------
__device__ __forceinline__ void select8k_ag(const unsigned int* __restrict__ hb,
                                            int rem, int* bin_out, int* rem_out) {
    __shared__ unsigned int cs[256];
    __shared__ unsigned int bs[32];
    __shared__ int s_chunk, s_bin, s_rem;
    int t = threadIdx.x;
    unsigned int s = 0;
#pragma unroll 8
    for (int i = 0; i < 32; ++i) s += agld(&hb[t * 32 + i]);
    cs[t] = s;
    __syncthreads();
    for (int d = 1; d < 256; d <<= 1) {
        unsigned int v = (t + d < 256) ? cs[t + d] : 0;
        __syncthreads();
        cs[t] += v;
        __syncthreads();
    }
    unsigned int St = cs[t];
    unsigned int St1 = (t < 255) ? cs[t + 1] : 0;
    if ((int)St >= rem && (t == 255 || (int)St1 < rem)) {
        s_chunk = t; s_rem = rem - (int)St1;
    }
    __syncthreads();
    int chunk = s_chunk, rem2 = s_rem;
    if (t < 32) bs[t] = agld(&hb[chunk * 32 + t]);
    __syncthreads();
    for (int d = 1; d < 32; d <<= 1) {
        unsigned int v = (t < 32 && t + d < 32) ? bs[t + d] : 0;
        __syncthreads();
        if (t < 32) bs[t] += v;
        __syncthreads();
    }
    if (t < 32) {
        unsigned int Sb = bs[t];
        unsigned int Sb1 = (t < 31) ? bs[t + 1] : 0;
        if ((int)Sb >= rem2 && (t == 31 || (int)Sb1 < rem2)) {
            s_bin = chunk * 32 + t; s_rem = rem2 - (int)Sb1;
        }
    }
    __syncthreads();
    *bin_out = s_bin;
    *rem_out = s_rem;
}

// ==================== kernel B: refine hist + strict-above sum + last-block finish ====================
__global__ __launch_bounds__(256) void k_B(const float4* __restrict__ score,
                                           const unsigned int* __restrict__ hist1,
                                           unsigned int* __restrict__ hist2,
                                           float* __restrict__ hsum,
                                           unsigned int* __restrict__ done,
                                           float* __restrict__ out) {
    __shared__ unsigned int lh[NB2];
    __shared__ float ls[NB2];
    __shared__ float red[4];
    __shared__ float rs[256];
    __shared__ int islast;
    int b = blockIdx.x >> 7;
    int seg = blockIdx.x & (SEGF - 1);
    int bin1, rem1;
    select4k(hist1 + (size_t)b * NB1, KTOP, &bin1, &rem1);   // hot in L2
    unsigned int t1 = (unsigned int)bin1;
    for (int i = threadIdx.x; i < NB2; i += 256) { lh[i] = 0; ls[i] = 0.f; }
    __syncthreads();
    const float4* p = score + ((size_t)b * HW + (size_t)seg * (HW / SEGF)) / 4;
    float sa = 0.f;   // sum of values strictly above the T1 coarse bin
    for (int i = threadIdx.x; i < (HW / SEGF) / 4; i += 256) {
        float4 v = p[i];
        float vv[4] = {v.x, v.y, v.z, v.w};
#pragma unroll
        for (int q = 0; q < 4; ++q) {
            unsigned int k = sortable(vv[q]);
            unsigned int cb = k >> 20;
            if (cb > t1) sa += vv[q];
            else if (cb == t1) {
                int sub = (k >> 7) & 0x1FFF;
                atomicAdd(&lh[sub], 1u);
                atomicAdd(&ls[sub], vv[q]);
            }
        }
    }
    __syncthreads();
    {
        unsigned int* hb = hist2 + (size_t)b * NB2;
        float* sb = hsum + (size_t)b * NB2;
        for (int i = threadIdx.x; i < NB2; i += 256) {
            unsigned int c = lh[i];
            if (c) { atomicAdd(&hb[i], c); atomicAdd(&sb[i], ls[i]); }
        }
    }
#pragma unroll
    for (int d = 32; d; d >>= 1) sa += __shfl_down(sa, d);
    if ((threadIdx.x & 63) == 0) red[threadIdx.x >> 6] = sa;
    __syncthreads();
    if (threadIdx.x == 0) {
        float tt = red[0] + red[1] + red[2] + red[3];
        if (tt != 0.f) atomicAdd(&out[b], tt);
    }
    // ---- done-counter handoff: syncthreads drains this block's atomics (vmcnt 0) ----
    __syncthreads();
    if (threadIdx.x == 0) {
        unsigned int prev = __hip_atomic_fetch_add(&done[b], 1u, __ATOMIC_RELAXED,
                                                   __HIP_MEMORY_SCOPE_AGENT);
        islast = (prev == (unsigned int)(SEGF - 1)) ? 1 : 0;
    }
    __syncthreads();
    if (islast) {                                  // block-uniform branch
        int bin, rem;
        select8k_ag(hist2 + (size_t)b * NB2, rem1, &bin, &rem);
        const unsigned int* sb = (const unsigned int*)(hsum + (size_t)b * NB2);
        float s = 0.f;
        for (int i = threadIdx.x; i < NB2; i += 256)
            if (i > bin) s += __uint_as_float(agld(&sb[i]));
        rs[threadIdx.x] = s;
        __syncthreads();
        for (int d = 128; d; d >>= 1) {
            if (threadIdx.x < d) rs[threadIdx.x] += rs[threadIdx.x + d];
            __syncthreads();
        }
        if (threadIdx.x == 0) {
            unsigned int K = (t1 << 20) | ((unsigned int)bin << 7);
            atomicAdd(&out[b], rs[0] + unsortable(K) * (float)rem);   // ties at bin edge
        }
    }
}

extern "C" void kernel_launch(void* const* d_in, const int* in_sizes, int n_in,
                              void* d_out, int out_size, void* d_ws, size_t ws_size,
                              hipStream_t stream) {
    const float* logit = (const float*)d_in[0];
    float* out = (float*)d_out;
    char* ws = (char*)d_ws;

    // workspace layout
    float*         ent   = (float*)(ws);                       // 8,388,608 B (boundary rows only)
    unsigned char* pred  = (unsigned char*)(ws + 8388608);     // 2,097,152 B
    float*         score = (float*)(ws + 10485760);            // 8,388,608 B
    unsigned int*  histb = (unsigned int*)(ws + 18874368);
    unsigned int*  hist1 = histb;                              // 16384 words
    unsigned int*  hist2 = histb + 16384;                      // 32768 words
    float*         hsum  = (float*)(histb + 49152);            // 32768 words
    unsigned int*  done  = histb + 82176;                      // 4 words (flags at 81920)

    k_init<<<81, 1024, 0, stream>>>(histb, out);
    k_A<<<NBLK, 1024, 0, stream>>>(logit, ent, pred, score, histb);
    k_B<<<BB * SEGF, 256, 0, stream>>>((const float4*)score, hist1, hist2, hsum, done, out);
}

// Round 5
// 267.529 us; speedup vs baseline: 2.7334x; 1.0836x over previous
//
#include <hip/hip_runtime.h>
#include <cstdint>
#include <cstddef>

#define BB 4
#define CC 19
#define HH 512
#define WW 1024
#define HW (HH*WW)          // 524288
#define HW4 (HW/4)          // 131072
#define KTOP 256
#define EPSF 1e-6f
#define NB1 4096            // coarse bins: key >> 20
#define NB2 8192            // refine bins: (key >> 7) & 0x1FFF
#define LSTRIDE 1032        // padded LDS row stride, data at col 4..1027
#define LOGC 2.9444389791664403f   // ln(19)

#define NSEG 64             // segments per image (8 rows each)
#define RPB 8               // rows per block
#define NBLK (BB*NSEG)      // 256 blocks, 1/CU, co-resident (capacity 2/CU)
#define TPB 1024            // 16 waves/CU

__device__ __forceinline__ unsigned int sortable(float x) {
    unsigned int u = __float_as_uint(x);
    return (u & 0x80000000u) ? ~u : (u | 0x80000000u);
}
__device__ __forceinline__ float unsortable(unsigned int K) {
    unsigned int u = (K & 0x80000000u) ? (K & 0x7FFFFFFFu) : ~K;
    return __uint_as_float(u);
}
// relaxed agent-scope atomics: cross-XCD coherent, NO L2 flush (Guideline 16)
__device__ __forceinline__ unsigned int agld(const unsigned int* p) {
    return __hip_atomic_load(p, __ATOMIC_RELAXED, __HIP_MEMORY_SCOPE_AGENT);
}

// wave-aggregated histogram add: one atomic per distinct bin per wave.
// Must be called with all 64 lanes active (uniform control flow).
__device__ __forceinline__ void wagg_add(unsigned int* hist, unsigned int bin) {
    unsigned long long todo = __ballot(1);
    int lane = threadIdx.x & 63;
    while (todo) {
        int leader = __ffsll((unsigned long long)todo) - 1;
        unsigned int lbin = (unsigned int)__shfl((int)bin, leader);
        unsigned long long mask = __ballot(bin == lbin);
        if (lane == leader) atomicAdd(&hist[lbin], (unsigned int)__popcll(mask));
        todo &= ~mask;
    }
}

// ---- LDS phase union ----
struct P1Mem {
    float ent_s[(RPB + 2) * LSTRIDE];          // 41280 B  (rows r0-1 .. r0+8)
    unsigned char pred_s[(RPB + 2) * LSTRIDE]; // 10320 B
    unsigned int lh1[NB1];                     // 16384 B
};
struct P2Mem {
    unsigned int lh2[NB2];                     // 32768 B
    float ls2[NB2];                            // 32768 B
};
union UMem { P1Mem p1; P2Mem p2; };            // 67984 B

// ---- top-down bin selection over 1024*CPT bins, 1024 threads, agld reads ----
template<int CPT>
__device__ __forceinline__ void sel_topdown(const unsigned int* __restrict__ hb,
                                            int rem, unsigned int* cs, unsigned int* bs,
                                            int* s3, int* bin_out, int* rem_out) {
    int t = threadIdx.x;
    unsigned int s = 0;
#pragma unroll
    for (int i = 0; i < CPT; ++i) s += agld(&hb[t * CPT + i]);
    cs[t] = s;
    __syncthreads();
    for (int d = 1; d < 1024; d <<= 1) {       // suffix scan over 1024 chunks
        unsigned int v = (t + d < 1024) ? cs[t + d] : 0;
        __syncthreads();
        cs[t] += v;
        __syncthreads();
    }
    unsigned int St = cs[t];
    unsigned int St1 = (t < 1023) ? cs[t + 1] : 0;
    if ((int)St >= rem && (t == 1023 || (int)St1 < rem)) {
        s3[0] = t; s3[2] = rem - (int)St1;
    }
    __syncthreads();
    int chunk = s3[0], rem2 = s3[2];
    if (t < CPT) bs[t] = agld(&hb[chunk * CPT + t]);
    __syncthreads();
    if (t == 0) {                              // tiny within-chunk suffix walk
        int acc = 0, bin = chunk * CPT, rr = rem2;
        for (int j = CPT - 1; j >= 0; --j) {
            acc += (int)bs[j];
            if (acc >= rem2) { bin = chunk * CPT + j; rr = rem2 - (acc - (int)bs[j]); break; }
        }
        s3[1] = bin; s3[2] = rr;
    }
    __syncthreads();
    *bin_out = s3[1];
    *rem_out = s3[2];
}

// ---- init: zero hist1|hist2|hsum|done1|done2 + out ----
__global__ __launch_bounds__(1024) void k_init(unsigned int* __restrict__ histb,
                                               float* __restrict__ out) {
    int i = blockIdx.x * 1024 + threadIdx.x;
    if (i < 81928) histb[i] = 0u;     // 81920 hist words + 4 done1 + 4 done2
    if (i < BB) out[i] = 0.f;
}

// ==================== single fused kernel (no cross-block data handoff) ====================
__global__ __launch_bounds__(1024, 4) void k_fused(const float* __restrict__ logit,
                                                   unsigned int* __restrict__ histb,
                                                   float* __restrict__ out) {
    __shared__ __align__(16) UMem U;
    __shared__ float lgt[48];
    __shared__ unsigned int cs[1024];
    __shared__ unsigned int bs[8];
    __shared__ int s3[3];
    __shared__ float red[16];
    __shared__ int islast;

    int tid = threadIdx.x;
    int tx = tid & 255;                 // quad column
    int ty = tid >> 8;                  // 0..3
    int b = blockIdx.x >> 6;            // image
    int seg = blockIdx.x & (NSEG - 1);  // 8-row segment
    int r0 = seg * RPB;

    unsigned int* hist1 = histb;                      // 4*4096 words
    unsigned int* hist2 = histb + 16384;              // 4*8192 words
    float*        hsum  = (float*)(histb + 49152);    // 4*8192 words
    unsigned int* done1 = histb + 81920;              // 4
    unsigned int* done2 = histb + 81924;              // 4

    if (tid < 48) {
        int nvi = tid >> 4, cnt = tid & 15;
        float nv = (nvi == 0) ? 4.f : (nvi == 1) ? 6.f : 9.f;
        lgt[tid] = __logf((float)cnt / nv + EPSF);
    }
    for (int i = tid; i < (RPB + 2) * LSTRIDE; i += TPB) { U.p1.ent_s[i] = 0.f; U.p1.pred_s[i] = 255; }
    for (int i = tid; i < NB1; i += TPB) U.p1.lh1[i] = 0;
    __syncthreads();

    // ---- P0: entropy + argmax for rows r0-1 .. r0+8 (redundant halo compute) ----
    {
        const float4* bb4 = (const float4*)logit + (size_t)b * CC * HW4;
        for (int t = tid; t < (RPB + 2) * 256; t += TPB) {   // 2560 quad-tasks
            int lr = t >> 8;                  // LDS row 0..9
            int cq = t & 255;                 // quad column
            int g = r0 - 1 + lr;              // global row
            if (g >= 0 && g < HH) {
                const float4* basep = bb4 + (size_t)g * 256 + cq;
                float e0 = 0.f, e1 = 0.f, e2 = 0.f, e3 = 0.f;
                float m0 = -1.f, m1 = -1.f, m2 = -1.f, m3 = -1.f;
                int a0 = 0, a1 = 0, a2 = 0, a3 = 0;
#pragma unroll
                for (int c = 0; c < CC; ++c) {
                    float4 p = basep[(size_t)c * HW4];
                    e0 -= p.x * __logf(p.x + EPSF); if (p.x > m0) { m0 = p.x; a0 = c; }
                    e1 -= p.y * __logf(p.y + EPSF); if (p.y > m1) { m1 = p.y; a1 = c; }
                    e2 -= p.z * __logf(p.z + EPSF); if (p.z > m2) { m2 = p.z; a2 = c; }
                    e3 -= p.w * __logf(p.w + EPSF); if (p.w > m3) { m3 = p.w; a3 = c; }
                }
                *(float4*)&U.p1.ent_s[lr * LSTRIDE + 4 + cq * 4] = make_float4(e0, e1, e2, e3);
                unsigned int pw = (unsigned int)a0 | ((unsigned int)a1 << 8) |
                                  ((unsigned int)a2 << 16) | ((unsigned int)a3 << 24);
                *(unsigned int*)&U.p1.pred_s[lr * LSTRIDE + 4 + cq * 4] = pw;
            }
        }
    }
    __syncthreads();

    // ---- P1: score 8 px/thread (rows r0+ty, r0+ty+4; cols 4tx..4tx+3) ----
    float sv[8];
#pragma unroll
    for (int it = 0; it < 2; ++it) {
        int k = ty + it * 4;                  // local pixel row; window = LDS rows k..k+2
        float r3[3][6];
        int p3[3][6];
#pragma unroll
        for (int rr = 0; rr < 3; ++rr) {
            const float* rowp = &U.p1.ent_s[(k + rr) * LSTRIDE + 4];
            const unsigned char* prow = &U.p1.pred_s[(k + rr) * LSTRIDE + 4];
            float4 m = *(const float4*)&rowp[tx * 4];
            r3[rr][0] = rowp[tx * 4 - 1];     // col pad (0) at w==0 edge
            r3[rr][1] = m.x; r3[rr][2] = m.y; r3[rr][3] = m.z; r3[rr][4] = m.w;
            r3[rr][5] = rowp[tx * 4 + 4];
            uchar4 pm = *(const uchar4*)&prow[tx * 4];
            p3[rr][0] = prow[tx * 4 - 1];     // 255 pad
            p3[rr][1] = pm.x; p3[rr][2] = pm.y; p3[rr][3] = pm.z; p3[rr][4] = pm.w;
            p3[rr][5] = prow[tx * 4 + 4];
        }
        int h = r0 + k;
        int hn = (h > 0) + (h < HH - 1) + 1;
#pragma unroll
        for (int q = 0; q < 4; ++q) {
            int w = tx * 4 + q;
            float es = 0.f;
#pragma unroll
            for (int i = 0; i < 9; ++i) es += r3[i / 3][q + i % 3];   // same add order
            int cls[9];
#pragma unroll
            for (int i = 0; i < 9; ++i) cls[i] = p3[i / 3][q + i % 3];
            int nv = hn * ((w > 0) + (w < WW - 1) + 1);
            float inv = 1.f / (float)nv;
            int nvi = (nv == 9) ? 2 : ((nv == 6) ? 1 : 0);
            const float* lg = &lgt[nvi * 16];
            float lsum = 0.f;
#pragma unroll
            for (int i = 0; i < 9; ++i) {
                int cnt = 0;
#pragma unroll
                for (int j = 0; j < 9; ++j) cnt += (cls[j] == cls[i]) ? 1 : 0;
                float lv = lg[cnt];
                lsum += (cls[i] != 255) ? lv : 0.f;
            }
            float imp = -inv * lsum;
            float v = (es * (1.f / (9.f * LOGC))) * (imp * (1.f / LOGC));
            sv[it * 4 + q] = v;
            wagg_add(U.p1.lh1, sortable(v) >> 20);   // aggregated: 1 atomic/distinct bin/wave
        }
    }
    __syncthreads();
    {
        unsigned int* hb = hist1 + (size_t)b * NB1;
        for (int i = tid; i < NB1; i += TPB) {
            unsigned int c = U.p1.lh1[i];
            if (c) atomicAdd(&hb[i], c);             // device-scope by default
        }
    }
    // ---- per-image barrier: syncthreads drains the block's atomics first ----
    __syncthreads();
    if (tid == 0) {
        __hip_atomic_fetch_add(&done1[b], 1u, __ATOMIC_RELAXED, __HIP_MEMORY_SCOPE_AGENT);
        while (agld(&done1[b]) < (unsigned int)NSEG) __builtin_amdgcn_s_sleep(8);
    }
    __syncthreads();

    // ---- P2: coarse select + refine hist + strict-above sum ----
    int bin1, rem1;
    sel_topdown<4>(hist1 + (size_t)b * NB1, KTOP, cs, bs, s3, &bin1, &rem1);
    unsigned int t1 = (unsigned int)bin1;
    for (int i = tid; i < NB2; i += TPB) { U.p2.lh2[i] = 0; U.p2.ls2[i] = 0.f; }
    __syncthreads();
    float sa = 0.f;                               // sum strictly above the T1 coarse bin
#pragma unroll
    for (int j = 0; j < 8; ++j) {
        float vv = sv[j];
        unsigned int k = sortable(vv);
        unsigned int cb = k >> 20;
        if (cb > t1) sa += vv;
        else if (cb == t1) {
            int sub = (k >> 7) & 0x1FFF;
            atomicAdd(&U.p2.lh2[sub], 1u);
            atomicAdd(&U.p2.ls2[sub], vv);
        }
    }
    __syncthreads();
    {
        unsigned int* hb = hist2 + (size_t)b * NB2;
        float* sb = hsum + (size_t)b * NB2;
        for (int i = tid; i < NB2; i += TPB) {
            unsigned int c = U.p2.lh2[i];
            if (c) { atomicAdd(&hb[i], c); atomicAdd(&sb[i], U.p2.ls2[i]); }
        }
    }
#pragma unroll
    for (int d = 32; d; d >>= 1) sa += __shfl_down(sa, d);
    if ((tid & 63) == 0) red[tid >> 6] = sa;
    __syncthreads();
    if (tid == 0) {
        float tt = 0.f;
#pragma unroll
        for (int i = 0; i < 16; ++i) tt += red[i];
        if (tt != 0.f) atomicAdd(&out[b], tt);
    }
    // ---- done-counter handoff: last block per image finishes ----
    __syncthreads();
    if (tid == 0) {
        unsigned int prev = __hip_atomic_fetch_add(&done2[b], 1u, __ATOMIC_RELAXED,
                                                   __HIP_MEMORY_SCOPE_AGENT);
        islast = (prev == (unsigned int)(NSEG - 1)) ? 1 : 0;
    }
    __syncthreads();
    if (islast) {                                  // block-uniform branch
        int bin, rem;
        sel_topdown<8>(hist2 + (size_t)b * NB2, rem1, cs, bs, s3, &bin, &rem);
        const unsigned int* sb = (const unsigned int*)(hsum + (size_t)b * NB2);
        float* rsf = (float*)cs;                   // reuse scan scratch
        float s = 0.f;
        for (int i = tid; i < NB2; i += TPB)
            if (i > bin) s += __uint_as_float(agld(&sb[i]));
        rsf[tid] = s;
        __syncthreads();
        for (int d = 512; d; d >>= 1) {
            if (tid < d) rsf[tid] += rsf[tid + d];
            __syncthreads();
        }
        if (tid == 0) {
            unsigned int K = (t1 << 20) | ((unsigned int)bin << 7);
            atomicAdd(&out[b], rsf[0] + unsortable(K) * (float)rem);  // ties at bin edge
        }
    }
}

extern "C" void kernel_launch(void* const* d_in, const int* in_sizes, int n_in,
                              void* d_out, int out_size, void* d_ws, size_t ws_size,
                              hipStream_t stream) {
    const float* logit = (const float*)d_in[0];
    float* out = (float*)d_out;
    unsigned int* histb = (unsigned int*)d_ws;     // hist1|hist2|hsum|done1|done2 = 81928 words

    k_init<<<81, 1024, 0, stream>>>(histb, out);
    k_fused<<<NBLK, TPB, 0, stream>>>(logit, histb, out);
}

// Round 6
// 264.115 us; speedup vs baseline: 2.7688x; 1.0129x over previous
//
#include <hip/hip_runtime.h>
#include <cstdint>
#include <cstddef>

#define BB 4
#define CC 19
#define HH 512
#define WW 1024
#define HW (HH*WW)          // 524288
#define HW4 (HW/4)          // 131072
#define KTOP 256
#define EPSF 1e-6f
#define NB1 4096            // coarse bins: key >> 20
#define NB2 8192            // refine bins: (key >> 7) & 0x1FFF
#define LSTRIDE 1032        // padded LDS row stride, data at col 4..1027
#define LOGC 2.9444389791664403f   // ln(19)

#define NSEG 64             // segments per image (8 rows each)
#define RPB 8               // rows per block
#define NBLK (BB*NSEG)      // 256 blocks, 1/CU, co-resident (capacity-proven)
#define TPB 1024            // 16 waves/CU

__device__ __forceinline__ unsigned int sortable(float x) {
    unsigned int u = __float_as_uint(x);
    return (u & 0x80000000u) ? ~u : (u | 0x80000000u);
}
__device__ __forceinline__ float unsortable(unsigned int K) {
    unsigned int u = (K & 0x80000000u) ? (K & 0x7FFFFFFFu) : ~K;
    return __uint_as_float(u);
}
// relaxed agent-scope atomics: cross-XCD coherent, NO L2 flush (Guideline 16)
__device__ __forceinline__ unsigned int agld(const unsigned int* p) {
    return __hip_atomic_load(p, __ATOMIC_RELAXED, __HIP_MEMORY_SCOPE_AGENT);
}

// ---- LDS phase union ----
struct P1Mem {
    float ent_s[(RPB + 2) * LSTRIDE];          // 41280 B  (rows r0-1 .. r0+8)
    unsigned char pred_s[(RPB + 2) * LSTRIDE]; // 10320 B
    unsigned int lh1[NB1];                     // 16384 B
};
struct P2Mem {
    unsigned int lh2[NB2];                     // 32768 B
    float ls2[NB2];                            // 32768 B
};
union UMem { P1Mem p1; P2Mem p2; };            // 67984 B

// ---- top-down bin selection over 1024*CPT bins, 1024 threads, agld reads ----
template<int CPT>
__device__ __forceinline__ void sel_topdown(const unsigned int* __restrict__ hb,
                                            int rem, unsigned int* cs, unsigned int* bs,
                                            int* s3, int* bin_out, int* rem_out) {
    int t = threadIdx.x;
    unsigned int s = 0;
#pragma unroll
    for (int i = 0; i < CPT; ++i) s += agld(&hb[t * CPT + i]);
    cs[t] = s;
    __syncthreads();
    for (int d = 1; d < 1024; d <<= 1) {       // suffix scan over 1024 chunks
        unsigned int v = (t + d < 1024) ? cs[t + d] : 0;
        __syncthreads();
        cs[t] += v;
        __syncthreads();
    }
    unsigned int St = cs[t];
    unsigned int St1 = (t < 1023) ? cs[t + 1] : 0;
    if ((int)St >= rem && (t == 1023 || (int)St1 < rem)) {
        s3[0] = t; s3[2] = rem - (int)St1;
    }
    __syncthreads();
    int chunk = s3[0], rem2 = s3[2];
    if (t < CPT) bs[t] = agld(&hb[chunk * CPT + t]);
    __syncthreads();
    if (t == 0) {                              // tiny within-chunk suffix walk
        int acc = 0, bin = chunk * CPT, rr = rem2;
        for (int j = CPT - 1; j >= 0; --j) {
            acc += (int)bs[j];
            if (acc >= rem2) { bin = chunk * CPT + j; rr = rem2 - (acc - (int)bs[j]); break; }
        }
        s3[1] = bin; s3[2] = rr;
    }
    __syncthreads();
    *bin_out = s3[1];
    *rem_out = s3[2];
}

// ---- init: zero hist1|hist2|hsum|done1|done2 + out ----
__global__ __launch_bounds__(1024) void k_init(unsigned int* __restrict__ histb,
                                               float* __restrict__ out) {
    int i = blockIdx.x * 1024 + threadIdx.x;
    if (i < 81928) histb[i] = 0u;     // 81920 hist words + 4 done1 + 4 done2
    if (i < BB) out[i] = 0.f;
}

// ==================== single fused kernel (no cross-block data handoff) ====================
__global__ __launch_bounds__(1024, 4) void k_fused(const float* __restrict__ logit,
                                                   unsigned int* __restrict__ histb,
                                                   float* __restrict__ out) {
    __shared__ __align__(16) UMem U;
    __shared__ float lgt[48];
    __shared__ unsigned int cs[1024];
    __shared__ unsigned int bs[8];
    __shared__ int s3[3];
    __shared__ float red[16];
    __shared__ int islast;

    int tid = threadIdx.x;
    int tx = tid & 255;                 // quad column
    int ty = tid >> 8;                  // 0..3
    int b = blockIdx.x >> 6;            // image
    int seg = blockIdx.x & (NSEG - 1);  // 8-row segment
    int r0 = seg * RPB;

    unsigned int* hist1 = histb;                      // 4*4096 words
    unsigned int* hist2 = histb + 16384;              // 4*8192 words
    float*        hsum  = (float*)(histb + 49152);    // 4*8192 words
    unsigned int* done1 = histb + 81920;              // 4
    unsigned int* done2 = histb + 81924;              // 4

    if (tid < 48) {
        int nvi = tid >> 4, cnt = tid & 15;
        float nv = (nvi == 0) ? 4.f : (nvi == 1) ? 6.f : 9.f;
        lgt[tid] = __logf((float)cnt / nv + EPSF);
    }
    for (int i = tid; i < (RPB + 2) * LSTRIDE; i += TPB) { U.p1.ent_s[i] = 0.f; U.p1.pred_s[i] = 255; }
    for (int i = tid; i < NB1; i += TPB) U.p1.lh1[i] = 0;
    __syncthreads();

    // ---- P0: entropy + argmax for rows r0-1 .. r0+8 (redundant halo compute) ----
    // All 19 class loads issued as one batch -> ~19 vmem in flight per wave (MLP).
    {
        const float4* bb4 = (const float4*)logit + (size_t)b * CC * HW4;
        for (int t = tid; t < (RPB + 2) * 256; t += TPB) {   // 2560 quad-tasks
            int lr = t >> 8;                  // LDS row 0..9
            int cq = t & 255;                 // quad column
            int g = r0 - 1 + lr;              // global row
            if (g < 0 || g >= HH) continue;
            const float4* basep = bb4 + (size_t)g * 256 + cq;
            float4 pr[19];                    // fully unrolled: compile-time indices
#pragma unroll
            for (int c = 0; c < CC; ++c) pr[c] = basep[(size_t)c * HW4];
            float e0 = 0.f, e1 = 0.f, e2 = 0.f, e3 = 0.f;
            float m0 = -1.f, m1 = -1.f, m2 = -1.f, m3 = -1.f;
            int a0 = 0, a1 = 0, a2 = 0, a3 = 0;
#pragma unroll
            for (int c = 0; c < CC; ++c) {
                float4 p = pr[c];
                e0 -= p.x * __logf(p.x + EPSF); if (p.x > m0) { m0 = p.x; a0 = c; }
                e1 -= p.y * __logf(p.y + EPSF); if (p.y > m1) { m1 = p.y; a1 = c; }
                e2 -= p.z * __logf(p.z + EPSF); if (p.z > m2) { m2 = p.z; a2 = c; }
                e3 -= p.w * __logf(p.w + EPSF); if (p.w > m3) { m3 = p.w; a3 = c; }
            }
            *(float4*)&U.p1.ent_s[lr * LSTRIDE + 4 + cq * 4] = make_float4(e0, e1, e2, e3);
            unsigned int pw = (unsigned int)a0 | ((unsigned int)a1 << 8) |
                              ((unsigned int)a2 << 16) | ((unsigned int)a3 << 24);
            *(unsigned int*)&U.p1.pred_s[lr * LSTRIDE + 4 + cq * 4] = pw;
        }
    }
    __syncthreads();

    // ---- P1: score 8 px/thread (rows r0+ty, r0+ty+4; cols 4tx..4tx+3) ----
    float sv[8];
#pragma unroll
    for (int it = 0; it < 2; ++it) {
        int k = ty + it * 4;                  // local pixel row; window = LDS rows k..k+2
        float r3[3][6];
        int p3[3][6];
#pragma unroll
        for (int rr = 0; rr < 3; ++rr) {
            const float* rowp = &U.p1.ent_s[(k + rr) * LSTRIDE + 4];
            const unsigned char* prow = &U.p1.pred_s[(k + rr) * LSTRIDE + 4];
            float4 m = *(const float4*)&rowp[tx * 4];
            r3[rr][0] = rowp[tx * 4 - 1];     // col pad (0) at w==0 edge
            r3[rr][1] = m.x; r3[rr][2] = m.y; r3[rr][3] = m.z; r3[rr][4] = m.w;
            r3[rr][5] = rowp[tx * 4 + 4];
            uchar4 pm = *(const uchar4*)&prow[tx * 4];
            p3[rr][0] = prow[tx * 4 - 1];     // 255 pad
            p3[rr][1] = pm.x; p3[rr][2] = pm.y; p3[rr][3] = pm.z; p3[rr][4] = pm.w;
            p3[rr][5] = prow[tx * 4 + 4];
        }
        int h = r0 + k;
        int hn = (h > 0) + (h < HH - 1) + 1;
#pragma unroll
        for (int q = 0; q < 4; ++q) {
            int w = tx * 4 + q;
            float es = 0.f;
#pragma unroll
            for (int i = 0; i < 9; ++i) es += r3[i / 3][q + i % 3];   // same add order
            int cls[9];
#pragma unroll
            for (int i = 0; i < 9; ++i) cls[i] = p3[i / 3][q + i % 3];
            int nv = hn * ((w > 0) + (w < WW - 1) + 1);
            float inv = 1.f / (float)nv;
            int nvi = (nv == 9) ? 2 : ((nv == 6) ? 1 : 0);
            const float* lg = &lgt[nvi * 16];
            float lsum = 0.f;
#pragma unroll
            for (int i = 0; i < 9; ++i) {
                int cnt = 0;
#pragma unroll
                for (int j = 0; j < 9; ++j) cnt += (cls[j] == cls[i]) ? 1 : 0;
                float lv = lg[cnt];
                lsum += (cls[i] != 255) ? lv : 0.f;
            }
            float imp = -inv * lsum;
            float v = (es * (1.f / (9.f * LOGC))) * (imp * (1.f / LOGC));
            sv[it * 4 + q] = v;
            atomicAdd(&U.p1.lh1[sortable(v) >> 20], 1u);   // plain LDS atomic (R0-proven)
        }
    }
    __syncthreads();
    {
        unsigned int* hb = hist1 + (size_t)b * NB1;
        for (int i = tid; i < NB1; i += TPB) {
            unsigned int c = U.p1.lh1[i];
            if (c) atomicAdd(&hb[i], c);             // device-scope by default
        }
    }
    // ---- per-image barrier: syncthreads drains the block's atomics first ----
    __syncthreads();
    if (tid == 0) {
        __hip_atomic_fetch_add(&done1[b], 1u, __ATOMIC_RELAXED, __HIP_MEMORY_SCOPE_AGENT);
        while (agld(&done1[b]) < (unsigned int)NSEG) __builtin_amdgcn_s_sleep(8);
    }
    __syncthreads();

    // ---- P2: coarse select + refine hist + strict-above sum ----
    int bin1, rem1;
    sel_topdown<4>(hist1 + (size_t)b * NB1, KTOP, cs, bs, s3, &bin1, &rem1);
    unsigned int t1 = (unsigned int)bin1;
    for (int i = tid; i < NB2; i += TPB) { U.p2.lh2[i] = 0; U.p2.ls2[i] = 0.f; }
    __syncthreads();
    float sa = 0.f;                               // sum strictly above the T1 coarse bin
#pragma unroll
    for (int j = 0; j < 8; ++j) {
        float vv = sv[j];
        unsigned int k = sortable(vv);
        unsigned int cb = k >> 20;
        if (cb > t1) sa += vv;
        else if (cb == t1) {
            int sub = (k >> 7) & 0x1FFF;
            atomicAdd(&U.p2.lh2[sub], 1u);
            atomicAdd(&U.p2.ls2[sub], vv);
        }
    }
    __syncthreads();
    {
        unsigned int* hb = hist2 + (size_t)b * NB2;
        float* sb = hsum + (size_t)b * NB2;
        for (int i = tid; i < NB2; i += TPB) {
            unsigned int c = U.p2.lh2[i];
            if (c) { atomicAdd(&hb[i], c); atomicAdd(&sb[i], U.p2.ls2[i]); }
        }
    }
#pragma unroll
    for (int d = 32; d; d >>= 1) sa += __shfl_down(sa, d);
    if ((tid & 63) == 0) red[tid >> 6] = sa;
    __syncthreads();
    if (tid == 0) {
        float tt = 0.f;
#pragma unroll
        for (int i = 0; i < 16; ++i) tt += red[i];
        if (tt != 0.f) atomicAdd(&out[b], tt);
    }
    // ---- done-counter handoff: last block per image finishes ----
    __syncthreads();
    if (tid == 0) {
        unsigned int prev = __hip_atomic_fetch_add(&done2[b], 1u, __ATOMIC_RELAXED,
                                                   __HIP_MEMORY_SCOPE_AGENT);
        islast = (prev == (unsigned int)(NSEG - 1)) ? 1 : 0;
    }
    __syncthreads();
    if (islast) {                                  // block-uniform branch
        int bin, rem;
        sel_topdown<8>(hist2 + (size_t)b * NB2, rem1, cs, bs, s3, &bin, &rem);
        const unsigned int* sb = (const unsigned int*)(hsum + (size_t)b * NB2);
        float* rsf = (float*)cs;                   // reuse scan scratch
        float s = 0.f;
        for (int i = tid; i < NB2; i += TPB)
            if (i > bin) s += __uint_as_float(agld(&sb[i]));
        rsf[tid] = s;
        __syncthreads();
        for (int d = 512; d; d >>= 1) {
            if (tid < d) rsf[tid] += rsf[tid + d];
            __syncthreads();
        }
        if (tid == 0) {
            unsigned int K = (t1 << 20) | ((unsigned int)bin << 7);
            atomicAdd(&out[b], rsf[0] + unsortable(K) * (float)rem);  // ties at bin edge
        }
    }
}

extern "C" void kernel_launch(void* const* d_in, const int* in_sizes, int n_in,
                              void* d_out, int out_size, void* d_ws, size_t ws_size,
                              hipStream_t stream) {
    const float* logit = (const float*)d_in[0];
    float* out = (float*)d_out;
    unsigned int* histb = (unsigned int*)d_ws;     // hist1|hist2|hsum|done1|done2 = 81928 words

    k_init<<<81, 1024, 0, stream>>>(histb, out);
    k_fused<<<NBLK, TPB, 0, stream>>>(logit, histb, out);
}